// Round 1
// baseline (533.443 us; speedup 1.0000x reference)
//
#include <hip/hip_runtime.h>
#include <math.h>

// ============================ CSR build ============================

__global__ void count_kernel(const int* __restrict__ dst, int* __restrict__ deg, int E) {
  int i = blockIdx.x * 256 + threadIdx.x;
  if (i < E) atomicAdd(&deg[dst[i]], 1);
}

// exclusive scan of (deg[i]+1)  (+1 = self loop), single block of 1024
__global__ void scan_kernel(const int* __restrict__ deg, int* __restrict__ rowptr, int n) {
  __shared__ int buf[1024];
  __shared__ int carry;
  if (threadIdx.x == 0) carry = 0;
  __syncthreads();
  for (int base = 0; base < n; base += 1024) {
    int i = base + (int)threadIdx.x;
    int v = (i < n) ? (deg[i] + 1) : 0;
    int incl = v;
    buf[threadIdx.x] = v;
    __syncthreads();
    for (int s = 1; s < 1024; s <<= 1) {
      int t = (threadIdx.x >= (unsigned)s) ? buf[threadIdx.x - s] : 0;
      __syncthreads();
      incl += t;
      buf[threadIdx.x] = incl;
      __syncthreads();
    }
    if (i < n) rowptr[i] = carry + incl - v;
    int total = buf[1023];
    __syncthreads();
    if (threadIdx.x == 0) carry += total;
    __syncthreads();
  }
  if (threadIdx.x == 0) rowptr[n] = carry;
}

__global__ void scatter_kernel(const int* __restrict__ src, const int* __restrict__ dst,
                               const int* __restrict__ rowptr, int* __restrict__ wp,
                               int* __restrict__ col, int E, int n) {
  int i = blockIdx.x * 256 + threadIdx.x;
  if (i < E) {
    int d = dst[i];
    int p = rowptr[d] + atomicAdd(&wp[d], 1);
    col[p] = src[i];
  } else if (i < E + n) {
    int d = i - E;
    int p = rowptr[d] + atomicAdd(&wp[d], 1);
    col[p] = d;
  }
}

// ============================ fp32 GEMM ============================
// C[M,N] = A[M,K] @ B[K,N] (+ bias[N]).  BM=BN=64, BK=16, 256 thr, 4x4/thr.

#define BM 64
#define BN 64
#define BK 16

__global__ __launch_bounds__(256) void gemm_kernel(
    const float* __restrict__ A, const float* __restrict__ B,
    float* __restrict__ C, const float* __restrict__ bias,
    int M, int N, int K) {
  __shared__ float As[BK][BM + 4];
  __shared__ float Bs[BK][BN];
  const int tid = threadIdx.x;
  const int bm = blockIdx.y * BM;
  const int bn = blockIdx.x * BN;
  const int am = tid >> 2;          // 0..63 (A tile row)
  const int ak = (tid & 3) << 2;    // 0,4,8,12 (A tile k, float4)
  const int bk = tid >> 4;          // 0..15 (B tile k)
  const int bnv = (tid & 15) << 2;  // 0..60 (B tile col, float4)
  const int tm = (tid >> 4) << 2;
  const int tn = (tid & 15) << 2;
  float acc[4][4] = {};
  for (int k0 = 0; k0 < K; k0 += BK) {
    float4 av = make_float4(0.f, 0.f, 0.f, 0.f);
    if (bm + am < M)
      av = *reinterpret_cast<const float4*>(A + (size_t)(bm + am) * K + k0 + ak);
    float4 bv = *reinterpret_cast<const float4*>(B + (size_t)(k0 + bk) * N + bn + bnv);
    As[ak + 0][am] = av.x; As[ak + 1][am] = av.y;
    As[ak + 2][am] = av.z; As[ak + 3][am] = av.w;
    *reinterpret_cast<float4*>(&Bs[bk][bnv]) = bv;
    __syncthreads();
#pragma unroll
    for (int k = 0; k < BK; ++k) {
      float a[4], b[4];
#pragma unroll
      for (int i = 0; i < 4; ++i) a[i] = As[k][tm + i];
#pragma unroll
      for (int j = 0; j < 4; ++j) b[j] = Bs[k][tn + j];
#pragma unroll
      for (int i = 0; i < 4; ++i)
#pragma unroll
        for (int j = 0; j < 4; ++j) acc[i][j] = fmaf(a[i], b[j], acc[i][j]);
    }
    __syncthreads();
  }
  float4 bz = make_float4(0.f, 0.f, 0.f, 0.f);
  if (bias) bz = *reinterpret_cast<const float4*>(bias + bn + tn);
#pragma unroll
  for (int i = 0; i < 4; ++i) {
    int m = bm + tm + i;
    if (m < M) {
      float4 o;
      o.x = acc[i][0] + bz.x; o.y = acc[i][1] + bz.y;
      o.z = acc[i][2] + bz.z; o.w = acc[i][3] + bz.w;
      *reinterpret_cast<float4*>(C + (size_t)m * N + bn + tn) = o;
    }
  }
}

// ==================== attention coefficients ====================
// a_s[n,h] = sum_f h[n,h,f]*att_src[h,f];  same for a_d.

__global__ void attcoef_kernel(const float* __restrict__ h, const float* __restrict__ att_src,
                               const float* __restrict__ att_dst, float* __restrict__ a_s,
                               float* __restrict__ a_d, int n) {
  int idx = blockIdx.x * 256 + threadIdx.x;
  if (idx >= n * 8) return;
  int node = idx >> 3, hd = idx & 7;
  const float4* hp = reinterpret_cast<const float4*>(h + (size_t)node * 512 + hd * 64);
  const float4* sp = reinterpret_cast<const float4*>(att_src + hd * 64);
  const float4* dp = reinterpret_cast<const float4*>(att_dst + hd * 64);
  float ss = 0.f, sd = 0.f;
#pragma unroll
  for (int q = 0; q < 16; ++q) {
    float4 hv = hp[q], sv = sp[q], dv = dp[q];
    ss = fmaf(hv.x, sv.x, fmaf(hv.y, sv.y, fmaf(hv.z, sv.z, fmaf(hv.w, sv.w, ss))));
    sd = fmaf(hv.x, dv.x, fmaf(hv.y, dv.y, fmaf(hv.z, dv.z, fmaf(hv.w, dv.w, sd))));
  }
  a_s[idx] = ss;
  a_d[idx] = sd;
}

// ==================== GAT aggregation (per-dst block) ====================
// One block (256 thr) per dst node. Edge softmax per head, then
// out[dst,f] = sum_e alpha[e,head(f)] * h[src_e,f]  (+bias, optional row softmax).

#define CH 32

__global__ __launch_bounds__(256) void gat_aggregate_kernel(
    const float* __restrict__ h, const float* __restrict__ a_s,
    const float* __restrict__ a_d, const int* __restrict__ rowptr,
    const int* __restrict__ col, const float* __restrict__ bias,
    float* __restrict__ out, int do_softmax) {
  const int node = blockIdx.x;
  const int tid = threadIdx.x;
  const int start = rowptr[node];
  const int deg = rowptr[node + 1] - start;
  __shared__ float s_ad[8];
  __shared__ float s_m[8], s_den[8];
  __shared__ float red[256];
  __shared__ float s_alpha[CH][8];
  __shared__ int s_col[CH];
  if (tid < 8) s_ad[tid] = a_d[(size_t)node * 8 + tid];
  __syncthreads();
  const int hd = tid & 7;
  // pass 1: per-head max of leaky_relu(a_s[src]+a_d[dst])
  float lmax = -1e30f;
  for (int i = tid; i < deg * 8; i += 256) {
    int e = i >> 3;
    int s = col[start + e];
    float v = a_s[(size_t)s * 8 + hd] + s_ad[hd];
    v = (v > 0.f) ? v : 0.2f * v;
    lmax = fmaxf(lmax, v);
  }
  red[tid] = lmax;
  __syncthreads();
  for (int s = 128; s >= 8; s >>= 1) {
    if (tid < s) red[tid] = fmaxf(red[tid], red[tid + s]);
    __syncthreads();
  }
  if (tid < 8) s_m[tid] = red[tid];
  __syncthreads();
  // pass 2: per-head sum of exp
  float lsum = 0.f;
  for (int i = tid; i < deg * 8; i += 256) {
    int e = i >> 3;
    int s = col[start + e];
    float v = a_s[(size_t)s * 8 + hd] + s_ad[hd];
    v = (v > 0.f) ? v : 0.2f * v;
    lsum += expf(v - s_m[hd]);
  }
  red[tid] = lsum;
  __syncthreads();
  for (int s = 128; s >= 8; s >>= 1) {
    if (tid < s) red[tid] += red[tid + s];
    __syncthreads();
  }
  if (tid < 8) s_den[tid] = red[tid] + 1e-16f;
  __syncthreads();
  // pass 3: chunked alpha + feature accumulation
  float acc0 = 0.f, acc1 = 0.f;
  const int f0 = tid, f1 = tid + 256;
  const int h0 = f0 >> 6, h1i = f1 >> 6;
  for (int c0 = 0; c0 < deg; c0 += CH) {
    int ce = min(CH, deg - c0);
    if (tid < ce) s_col[tid] = col[start + c0 + tid];
    for (int i = tid; i < ce * 8; i += 256) {
      int e = i >> 3;
      int hh = i & 7;
      int s = col[start + c0 + e];
      float v = a_s[(size_t)s * 8 + hh] + s_ad[hh];
      v = (v > 0.f) ? v : 0.2f * v;
      s_alpha[e][hh] = expf(v - s_m[hh]) / s_den[hh];
    }
    __syncthreads();
    for (int e = 0; e < ce; ++e) {
      const float* hp = h + (size_t)s_col[e] * 512;
      acc0 = fmaf(hp[f0], s_alpha[e][h0], acc0);
      acc1 = fmaf(hp[f1], s_alpha[e][h1i], acc1);
    }
    __syncthreads();
  }
  acc0 += bias[f0];
  acc1 += bias[f1];
  if (!do_softmax) {
    out[(size_t)node * 512 + f0] = acc0;
    out[(size_t)node * 512 + f1] = acc1;
  } else {
    red[tid] = fmaxf(acc0, acc1);
    __syncthreads();
    for (int s = 128; s >= 1; s >>= 1) {
      if (tid < s) red[tid] = fmaxf(red[tid], red[tid + s]);
      __syncthreads();
    }
    float mm = red[0];
    __syncthreads();
    float e0 = expf(acc0 - mm), e1 = expf(acc1 - mm);
    red[tid] = e0 + e1;
    __syncthreads();
    for (int s = 128; s >= 1; s >>= 1) {
      if (tid < s) red[tid] += red[tid + s];
      __syncthreads();
    }
    float inv = 1.f / red[0];
    out[(size_t)node * 512 + f0] = e0 * inv;
    out[(size_t)node * 512 + f1] = e1 * inv;
  }
}

// ==================== LSTM prep + activation ====================
// Only i,g,o gates are needed (f gate multiplies 0). Pack 192 columns:
// jp<64 -> j=jp (i), 64<=jp<128 -> j=jp+64 (g), 128<=jp<192 -> j=jp+64 (o).

__global__ void prep_lstm_kernel(const float* __restrict__ W_ih, const float* __restrict__ b_ih,
                                 const float* __restrict__ b_hh, float* __restrict__ Wt,
                                 float* __restrict__ bsum) {
  int idx = blockIdx.x * 256 + threadIdx.x;
  if (idx < 512 * 192) {
    int k = idx / 192, jp = idx - k * 192;
    int j = (jp < 64) ? jp : jp + 64;
    Wt[idx] = W_ih[(size_t)j * 512 + k];
  }
  if (idx < 192) {
    int j = (idx < 64) ? idx : idx + 64;
    bsum[idx] = b_ih[j] + b_hh[j];
  }
}

__global__ void lstm_act_kernel(const float* __restrict__ gates, float* __restrict__ h2, int n) {
  int idx = blockIdx.x * 256 + threadIdx.x;
  if (idx >= n * 64) return;
  int node = idx >> 6, j = idx & 63;
  const float* g = gates + (size_t)node * 192;
  float iv = g[j], gv = g[64 + j], ov = g[128 + j];
  float c = (1.f / (1.f + expf(-iv))) * tanhf(gv);
  float hh = (1.f / (1.f + expf(-ov))) * tanhf(c);
  h2[idx] = fmaxf(hh, 0.f);  // fused relu
}

// ============================ launch ============================

extern "C" void kernel_launch(void* const* d_in, const int* in_sizes, int n_in,
                              void* d_out, int out_size, void* d_ws, size_t ws_size,
                              hipStream_t stream) {
  const float* x      = (const float*)d_in[0];
  const int*   ei     = (const int*)d_in[1];
  const float* W1     = (const float*)d_in[3];
  const float* att_s1 = (const float*)d_in[4];
  const float* att_d1 = (const float*)d_in[5];
  const float* bias1  = (const float*)d_in[6];
  const float* W_ih   = (const float*)d_in[7];
  const float* b_ih   = (const float*)d_in[9];
  const float* b_hh   = (const float*)d_in[10];
  const float* W2     = (const float*)d_in[11];
  const float* att_s2 = (const float*)d_in[12];
  const float* att_d2 = (const float*)d_in[13];
  const float* bias2  = (const float*)d_in[14];
  float* out = (float*)d_out;

  const int N = in_sizes[0] / 128;
  const int E = in_sizes[1] / 2;
  const int* src = ei;
  const int* dst = ei + E;

  char* p = (char*)d_ws;
  auto alloc = [&](size_t bytes) {
    char* r = p;
    p += (bytes + 255) & ~(size_t)255;
    return r;
  };
  float* bufA = (float*)alloc((size_t)N * 512 * 4);  // h1, later gates+h2
  float* bufB = (float*)alloc((size_t)N * 512 * 4);  // g1, later h3
  float* a_s1 = (float*)alloc((size_t)N * 8 * 4);
  float* a_d1 = (float*)alloc((size_t)N * 8 * 4);
  float* a_s2 = (float*)alloc((size_t)N * 8 * 4);
  float* a_d2 = (float*)alloc((size_t)N * 8 * 4);
  float* Wt   = (float*)alloc((size_t)512 * 192 * 4);
  float* bsum = (float*)alloc(192 * 4);
  int* deg    = (int*)alloc((size_t)2 * N * 4);  // deg + wp adjacent (one memset)
  int* wp     = deg + N;
  int* rowptr = (int*)alloc((size_t)(N + 1) * 4);
  int* col    = (int*)alloc((size_t)(E + N) * 4);

  float* h1 = bufA;
  float* g1 = bufB;
  float* gates = bufA;                       // h1 dead after aggregate1
  float* h2 = bufA + (size_t)N * 192;        // after gates region
  float* h3 = bufB;                          // g1 dead after lstm gemm

  // ---- CSR build (same work every call; graph-capture safe) ----
  hipMemsetAsync(deg, 0, (size_t)2 * N * 4, stream);
  count_kernel<<<(E + 255) / 256, 256, 0, stream>>>(dst, deg, E);
  scan_kernel<<<1, 1024, 0, stream>>>(deg, rowptr, N);
  scatter_kernel<<<(E + N + 255) / 256, 256, 0, stream>>>(src, dst, rowptr, wp, col, E, N);

  // ---- GATConv1 ----
  {
    dim3 g(512 / 64, (N + 63) / 64);
    gemm_kernel<<<g, 256, 0, stream>>>(x, W1, h1, nullptr, N, 512, 128);
  }
  attcoef_kernel<<<(N * 8 + 255) / 256, 256, 0, stream>>>(h1, att_s1, att_d1, a_s1, a_d1, N);
  gat_aggregate_kernel<<<N, 256, 0, stream>>>(h1, a_s1, a_d1, rowptr, col, bias1, g1, 0);

  // ---- LSTM (single step, h0=c0=0) ----
  prep_lstm_kernel<<<(512 * 192 + 255) / 256, 256, 0, stream>>>(W_ih, b_ih, b_hh, Wt, bsum);
  {
    dim3 g(192 / 64, (N + 63) / 64);
    gemm_kernel<<<g, 256, 0, stream>>>(g1, Wt, gates, bsum, N, 192, 512);
  }
  lstm_act_kernel<<<(N * 64 + 255) / 256, 256, 0, stream>>>(gates, h2, N);

  // ---- GATConv2 + fused softmax ----
  {
    dim3 g(512 / 64, (N + 63) / 64);
    gemm_kernel<<<g, 256, 0, stream>>>(h2, W2, h3, nullptr, N, 512, 64);
  }
  attcoef_kernel<<<(N * 8 + 255) / 256, 256, 0, stream>>>(h3, att_s2, att_d2, a_s2, a_d2, N);
  gat_aggregate_kernel<<<N, 256, 0, stream>>>(h3, a_s2, a_d2, rowptr, col, bias2, out, 1);
}

// Round 2
// 481.080 us; speedup vs baseline: 1.1088x; 1.1088x over previous
//
#include <hip/hip_runtime.h>
#include <math.h>

// ============================ CSR build ============================

__global__ void count_kernel(const int* __restrict__ dst, int* __restrict__ deg, int E) {
  int i = blockIdx.x * 256 + threadIdx.x;
  if (i < E) atomicAdd(&deg[dst[i]], 1);
}

// exclusive scan of (deg[i]+1)  (+1 = self loop), single block of 1024
__global__ void scan_kernel(const int* __restrict__ deg, int* __restrict__ rowptr, int n) {
  __shared__ int buf[1024];
  __shared__ int carry;
  if (threadIdx.x == 0) carry = 0;
  __syncthreads();
  for (int base = 0; base < n; base += 1024) {
    int i = base + (int)threadIdx.x;
    int v = (i < n) ? (deg[i] + 1) : 0;
    int incl = v;
    buf[threadIdx.x] = v;
    __syncthreads();
    for (int s = 1; s < 1024; s <<= 1) {
      int t = (threadIdx.x >= (unsigned)s) ? buf[threadIdx.x - s] : 0;
      __syncthreads();
      incl += t;
      buf[threadIdx.x] = incl;
      __syncthreads();
    }
    if (i < n) rowptr[i] = carry + incl - v;
    int total = buf[1023];
    __syncthreads();
    if (threadIdx.x == 0) carry += total;
    __syncthreads();
  }
  if (threadIdx.x == 0) rowptr[n] = carry;
}

__global__ void scatter_kernel(const int* __restrict__ src, const int* __restrict__ dst,
                               const int* __restrict__ rowptr, int* __restrict__ wp,
                               int* __restrict__ col, int E, int n) {
  int i = blockIdx.x * 256 + threadIdx.x;
  if (i < E) {
    int d = dst[i];
    int p = rowptr[d] + atomicAdd(&wp[d], 1);
    col[p] = src[i];
  } else if (i < E + n) {
    int d = i - E;
    int p = rowptr[d] + atomicAdd(&wp[d], 1);
    col[p] = d;
  }
}

// ============================ fp32 GEMM ============================
// C[M,*] = A[M,K] @ B[K,*] (+bias). Strided/batched: blockIdx.z adds
// aZ/bZ/cZ/biasZ element offsets (per-head projection GEMMs).
// BM=BN=64, BK=16, 256 thr, 4x4 per thread.

#define BM 64
#define BN 64
#define BK 16

__global__ __launch_bounds__(256) void gemm_kernel(
    const float* __restrict__ A, const float* __restrict__ B,
    float* __restrict__ C, const float* __restrict__ bias,
    int M, int K, int lda, int ldb, int ldc,
    int aZ, int bZ, int cZ, int biasZ) {
  __shared__ float As[BK][BM + 4];
  __shared__ float Bs[BK][BN];
  const int z = blockIdx.z;
  A += (size_t)z * aZ;
  B += (size_t)z * bZ;
  C += (size_t)z * cZ;
  const int tid = threadIdx.x;
  const int bm = blockIdx.y * BM;
  const int bn = blockIdx.x * BN;
  const int am = tid >> 2;          // 0..63 (A tile row)
  const int ak = (tid & 3) << 2;    // 0,4,8,12 (A tile k, float4)
  const int bk = tid >> 4;          // 0..15 (B tile k)
  const int bnv = (tid & 15) << 2;  // 0..60 (B tile col, float4)
  const int tm = (tid >> 4) << 2;
  const int tn = (tid & 15) << 2;
  float acc[4][4] = {};
  for (int k0 = 0; k0 < K; k0 += BK) {
    float4 av = make_float4(0.f, 0.f, 0.f, 0.f);
    if (bm + am < M)
      av = *reinterpret_cast<const float4*>(A + (size_t)(bm + am) * lda + k0 + ak);
    float4 bv = *reinterpret_cast<const float4*>(B + (size_t)(k0 + bk) * ldb + bn + bnv);
    As[ak + 0][am] = av.x; As[ak + 1][am] = av.y;
    As[ak + 2][am] = av.z; As[ak + 3][am] = av.w;
    *reinterpret_cast<float4*>(&Bs[bk][bnv]) = bv;
    __syncthreads();
#pragma unroll
    for (int k = 0; k < BK; ++k) {
      float a[4], b[4];
#pragma unroll
      for (int i = 0; i < 4; ++i) a[i] = As[k][tm + i];
#pragma unroll
      for (int j = 0; j < 4; ++j) b[j] = Bs[k][tn + j];
#pragma unroll
      for (int i = 0; i < 4; ++i)
#pragma unroll
        for (int j = 0; j < 4; ++j) acc[i][j] = fmaf(a[i], b[j], acc[i][j]);
    }
    __syncthreads();
  }
  float4 bz = make_float4(0.f, 0.f, 0.f, 0.f);
  if (bias) bz = *reinterpret_cast<const float4*>(bias + (size_t)z * biasZ + bn + tn);
#pragma unroll
  for (int i = 0; i < 4; ++i) {
    int m = bm + tm + i;
    if (m < M) {
      float4 o;
      o.x = acc[i][0] + bz.x; o.y = acc[i][1] + bz.y;
      o.z = acc[i][2] + bz.z; o.w = acc[i][3] + bz.w;
      *reinterpret_cast<float4*>(C + (size_t)m * ldc + bn + tn) = o;
    }
  }
}

// ==================== attention weight-vector prep ====================
// watt[f][c] = sum_j W[f, k*64+j] * att[k][j],  c<8: att_src (k=c), c>=8: att_dst (k=c-8)

__global__ void prep_watt_kernel(const float* __restrict__ W, const float* __restrict__ att_s,
                                 const float* __restrict__ att_d, float* __restrict__ watt,
                                 int F) {
  int idx = blockIdx.x * 256 + threadIdx.x;
  if (idx >= F * 16) return;
  int f = idx >> 4, c = idx & 15;
  int k = c & 7;
  const float* att = ((c < 8) ? att_s : att_d) + k * 64;
  const float* w = W + (size_t)f * 512 + k * 64;
  float s = 0.f;
#pragma unroll
  for (int j = 0; j < 64; ++j) s = fmaf(w[j], att[j], s);
  watt[idx] = s;
}

// ==================== attention coefficients ====================
// a_{s,d}[n,k] = sum_f feat[n,f] * watt[f][c].  16 nodes per block, LDS-staged.

template <int F>
__global__ __launch_bounds__(256) void attcoef_kernel(
    const float* __restrict__ feat, const float* __restrict__ watt,
    float* __restrict__ a_s, float* __restrict__ a_d, int n) {
  __shared__ float rows[16 * F];
  __shared__ float wbuf[F * 16];
  const int n0 = blockIdx.x * 16;
  const int tid = threadIdx.x;
  if (n0 + 16 <= n) {
    const float4* g = reinterpret_cast<const float4*>(feat + (size_t)n0 * F);
    float4* l = reinterpret_cast<float4*>(rows);
    for (int i = tid; i < 16 * F / 4; i += 256) l[i] = g[i];
  } else {
    for (int i = tid; i < 16 * F; i += 256) {
      int r = i / F;
      rows[i] = (n0 + r < n) ? feat[(size_t)(n0 + r) * F + (i - r * F)] : 0.f;
    }
  }
  {
    const float4* g = reinterpret_cast<const float4*>(watt);
    float4* l = reinterpret_cast<float4*>(wbuf);
    for (int i = tid; i < F * 16 / 4; i += 256) l[i] = g[i];
  }
  __syncthreads();
  const int local = tid >> 4, c = tid & 15;
  float s = 0.f;
#pragma unroll 8
  for (int f = 0; f < F; ++f) s = fmaf(rows[local * F + f], wbuf[f * 16 + c], s);
  const int node = n0 + local;
  if (node < n) {
    if (c < 8) a_s[(size_t)node * 8 + c] = s;
    else       a_d[(size_t)node * 8 + (c - 8)] = s;
  }
}

// ==================== GAT pre-aggregation (per-dst block) ====================
// One block per dst node. Edge softmax per head on (a_s[src]+a_d[dst]); then
// agg[dst,k,f] = sum_e alpha[e,k] * feat[src_e,f]   (projection happens later).

#define CH 32

template <int F>
__global__ __launch_bounds__(256) void gat_aggregate_kernel(
    const float* __restrict__ feat, const float* __restrict__ a_s,
    const float* __restrict__ a_d, const int* __restrict__ rowptr,
    const int* __restrict__ col, float* __restrict__ agg) {
  constexpr int G = 256 / F;   // dup groups (F=128 -> 2, F=64 -> 4)
  constexpr int HPT = 8 / G;   // heads per thread (4 or 2)
  const int node = blockIdx.x;
  const int tid = threadIdx.x;
  const int start = rowptr[node];
  const int deg = rowptr[node + 1] - start;
  __shared__ float s_ad[8];
  __shared__ float s_m[8], s_den[8];
  __shared__ float red[256];
  __shared__ float s_alpha[CH][8];
  __shared__ int s_col[CH];
  if (tid < 8) s_ad[tid] = a_d[(size_t)node * 8 + tid];
  __syncthreads();
  const int hd = tid & 7;
  // pass 1: per-head max of leaky_relu(a_s[src]+a_d[dst])
  float lmax = -1e30f;
  for (int i = tid; i < deg * 8; i += 256) {
    int e = i >> 3;
    int s = col[start + e];
    float v = a_s[(size_t)s * 8 + hd] + s_ad[hd];
    v = (v > 0.f) ? v : 0.2f * v;
    lmax = fmaxf(lmax, v);
  }
  red[tid] = lmax;
  __syncthreads();
  for (int s = 128; s >= 8; s >>= 1) {
    if (tid < s) red[tid] = fmaxf(red[tid], red[tid + s]);
    __syncthreads();
  }
  if (tid < 8) s_m[tid] = red[tid];
  __syncthreads();
  // pass 2: per-head sum of exp
  float lsum = 0.f;
  for (int i = tid; i < deg * 8; i += 256) {
    int e = i >> 3;
    int s = col[start + e];
    float v = a_s[(size_t)s * 8 + hd] + s_ad[hd];
    v = (v > 0.f) ? v : 0.2f * v;
    lsum += expf(v - s_m[hd]);
  }
  red[tid] = lsum;
  __syncthreads();
  for (int s = 128; s >= 8; s >>= 1) {
    if (tid < s) red[tid] += red[tid + s];
    __syncthreads();
  }
  if (tid < 8) s_den[tid] = red[tid] + 1e-16f;
  __syncthreads();
  // pass 3: chunked alpha + raw-feature accumulation
  const int f = tid & (F - 1);
  const int p = tid / F;  // 0..G-1
  float acc[HPT];
#pragma unroll
  for (int j = 0; j < HPT; ++j) acc[j] = 0.f;
  for (int c0 = 0; c0 < deg; c0 += CH) {
    int ce = min(CH, deg - c0);
    if (tid < ce) s_col[tid] = col[start + c0 + tid];
    for (int i = tid; i < ce * 8; i += 256) {
      int e = i >> 3;
      int hh = i & 7;
      int s = col[start + c0 + e];
      float v = a_s[(size_t)s * 8 + hh] + s_ad[hh];
      v = (v > 0.f) ? v : 0.2f * v;
      s_alpha[e][hh] = expf(v - s_m[hh]) / s_den[hh];
    }
    __syncthreads();
    for (int e = 0; e < ce; ++e) {
      float xv = feat[(size_t)s_col[e] * F + f];
#pragma unroll
      for (int j = 0; j < HPT; ++j) acc[j] = fmaf(s_alpha[e][p * HPT + j], xv, acc[j]);
    }
    __syncthreads();
  }
#pragma unroll
  for (int j = 0; j < HPT; ++j)
    agg[(size_t)node * (8 * F) + (size_t)(p * HPT + j) * F + f] = acc[j];
}

// ==================== LSTM prep + activation ====================
// Only i,g,o gates needed (f gate multiplies c0=0). Packed 192 columns:
// jp<64 -> i (j=jp), 64..127 -> g (j=jp+64), 128..191 -> o (j=jp+64).

__global__ void prep_lstm_kernel(const float* __restrict__ W_ih, const float* __restrict__ b_ih,
                                 const float* __restrict__ b_hh, float* __restrict__ Wt,
                                 float* __restrict__ bsum) {
  int idx = blockIdx.x * 256 + threadIdx.x;
  if (idx < 512 * 192) {
    int k = idx / 192, jp = idx - k * 192;
    int j = (jp < 64) ? jp : jp + 64;
    Wt[idx] = W_ih[(size_t)j * 512 + k];
  }
  if (idx < 192) {
    int j = (idx < 64) ? idx : idx + 64;
    bsum[idx] = b_ih[j] + b_hh[j];
  }
}

__global__ void lstm_act_kernel(const float* __restrict__ gates, float* __restrict__ h2, int n) {
  int idx = blockIdx.x * 256 + threadIdx.x;
  if (idx >= n * 64) return;
  int node = idx >> 6, j = idx & 63;
  const float* g = gates + (size_t)node * 192;
  float iv = g[j], gv = g[64 + j], ov = g[128 + j];
  float c = (1.f / (1.f + expf(-iv))) * tanhf(gv);
  float hh = (1.f / (1.f + expf(-ov))) * tanhf(c);
  h2[idx] = fmaxf(hh, 0.f);  // fused relu
}

// ==================== final row softmax (512 wide) ====================

__global__ __launch_bounds__(256) void softmax512_kernel(const float* __restrict__ in,
                                                         float* __restrict__ out) {
  const int node = blockIdx.x;
  const int tid = threadIdx.x;
  __shared__ float red[256];
  float v0 = in[(size_t)node * 512 + tid];
  float v1 = in[(size_t)node * 512 + 256 + tid];
  red[tid] = fmaxf(v0, v1);
  __syncthreads();
  for (int s = 128; s >= 1; s >>= 1) {
    if (tid < s) red[tid] = fmaxf(red[tid], red[tid + s]);
    __syncthreads();
  }
  float mm = red[0];
  __syncthreads();
  float e0 = expf(v0 - mm), e1 = expf(v1 - mm);
  red[tid] = e0 + e1;
  __syncthreads();
  for (int s = 128; s >= 1; s >>= 1) {
    if (tid < s) red[tid] += red[tid + s];
    __syncthreads();
  }
  float inv = 1.f / red[0];
  out[(size_t)node * 512 + tid] = e0 * inv;
  out[(size_t)node * 512 + 256 + tid] = e1 * inv;
}

// ============================ launch ============================

extern "C" void kernel_launch(void* const* d_in, const int* in_sizes, int n_in,
                              void* d_out, int out_size, void* d_ws, size_t ws_size,
                              hipStream_t stream) {
  const float* x      = (const float*)d_in[0];
  const int*   ei     = (const int*)d_in[1];
  const float* W1     = (const float*)d_in[3];
  const float* att_s1 = (const float*)d_in[4];
  const float* att_d1 = (const float*)d_in[5];
  const float* bias1  = (const float*)d_in[6];
  const float* W_ih   = (const float*)d_in[7];
  const float* b_ih   = (const float*)d_in[9];
  const float* b_hh   = (const float*)d_in[10];
  const float* W2     = (const float*)d_in[11];
  const float* att_s2 = (const float*)d_in[12];
  const float* att_d2 = (const float*)d_in[13];
  const float* bias2  = (const float*)d_in[14];
  float* out = (float*)d_out;

  const int N = in_sizes[0] / 128;
  const int E = in_sizes[1] / 2;
  const int* src = ei;
  const int* dst = ei + E;

  char* p = (char*)d_ws;
  auto alloc = [&](size_t bytes) {
    char* r = p;
    p += (bytes + 255) & ~(size_t)255;
    return r;
  };
  // slot A: agg1 [N,8,128]; later reused for gates+h2+agg2
  float* slotA = (float*)alloc((size_t)N * 1024 * 4);
  // slot B: g1 [N,512]; later reused for h3p
  float* slotB = (float*)alloc((size_t)N * 512 * 4);
  float* a_s1 = (float*)alloc((size_t)N * 8 * 4);
  float* a_d1 = (float*)alloc((size_t)N * 8 * 4);
  float* a_s2 = (float*)alloc((size_t)N * 8 * 4);
  float* a_d2 = (float*)alloc((size_t)N * 8 * 4);
  float* watt1 = (float*)alloc(128 * 16 * 4);
  float* watt2 = (float*)alloc(64 * 16 * 4);
  float* Wt   = (float*)alloc((size_t)512 * 192 * 4);
  float* bsum = (float*)alloc(192 * 4);
  int* deg    = (int*)alloc((size_t)2 * N * 4);  // deg + wp adjacent (one memset)
  int* wp     = deg + N;
  int* rowptr = (int*)alloc((size_t)(N + 1) * 4);
  int* col    = (int*)alloc((size_t)(E + N) * 4);

  float* agg1  = slotA;                        // [N,8,128], dead after proj1
  float* g1    = slotB;                        // [N,512], dead after LSTM gemm
  float* gates = slotA;                        // [N,192]
  float* h2    = slotA + (size_t)N * 192;      // [N,64]
  float* agg2  = slotA + (size_t)N * 320;      // [N,8,64] (320+512=832 <= 1024)
  float* h3p   = slotB;                        // [N,512] pre-softmax logits

  // ---- CSR build (identical work every call; graph-capture safe) ----
  hipMemsetAsync(deg, 0, (size_t)2 * N * 4, stream);
  count_kernel<<<(E + 255) / 256, 256, 0, stream>>>(dst, deg, E);
  scan_kernel<<<1, 1024, 0, stream>>>(deg, rowptr, N);
  scatter_kernel<<<(E + N + 255) / 256, 256, 0, stream>>>(src, dst, rowptr, wp, col, E, N);

  // ---- weight prep ----
  prep_watt_kernel<<<(128 * 16 + 255) / 256, 256, 0, stream>>>(W1, att_s1, att_d1, watt1, 128);
  prep_watt_kernel<<<(64 * 16 + 255) / 256, 256, 0, stream>>>(W2, att_s2, att_d2, watt2, 64);
  prep_lstm_kernel<<<(512 * 192 + 255) / 256, 256, 0, stream>>>(W_ih, b_ih, b_hh, Wt, bsum);

  // ---- GATConv1: coeffs on raw x, aggregate raw x, then project ----
  attcoef_kernel<128><<<(N + 15) / 16, 256, 0, stream>>>(x, watt1, a_s1, a_d1, N);
  gat_aggregate_kernel<128><<<N, 256, 0, stream>>>(x, a_s1, a_d1, rowptr, col, agg1);
  {
    dim3 g(1, (N + 63) / 64, 8);  // per-head: [N,128] @ W1[:,k*64:+64] -> g1[:,k*64:+64]
    gemm_kernel<<<g, 256, 0, stream>>>(agg1, W1, g1, bias1,
                                       N, 128, 1024, 512, 512, 128, 64, 64, 64);
  }

  // ---- LSTM (single step, h0=c0=0) ----
  {
    dim3 g(192 / 64, (N + 63) / 64, 1);
    gemm_kernel<<<g, 256, 0, stream>>>(g1, Wt, gates, bsum,
                                       N, 512, 512, 192, 192, 0, 0, 0, 0);
  }
  lstm_act_kernel<<<(N * 64 + 255) / 256, 256, 0, stream>>>(gates, h2, N);

  // ---- GATConv2: coeffs on h2, aggregate h2, project, row softmax ----
  attcoef_kernel<64><<<(N + 15) / 16, 256, 0, stream>>>(h2, watt2, a_s2, a_d2, N);
  gat_aggregate_kernel<64><<<N, 256, 0, stream>>>(h2, a_s2, a_d2, rowptr, col, agg2);
  {
    dim3 g(1, (N + 63) / 64, 8);  // per-head: [N,64] @ W2[:,k*64:+64] -> h3p[:,k*64:+64]
    gemm_kernel<<<g, 256, 0, stream>>>(agg2, W2, h3p, bias2,
                                       N, 64, 512, 512, 512, 64, 64, 64, 64);
  }
  softmax512_kernel<<<N, 256, 0, stream>>>(h3p, out);
}